// Round 1
// baseline (176.119 us; speedup 1.0000x reference)
//
#include <hip/hip_runtime.h>
#include <math.h>

// Problem constants (KWinners2d: B=32, H=56, W=56, C=128)
#define NROW 32
#define NPR  401408        // elements per row = 56*56*128
#define N4   100352        // float4 per row
#define NCH  128
#define NBIN 4096
#define EQCAP 8192

struct RowState { unsigned p1, krem1, p2, krem2, tkey, cutoff, pad0, pad1; };

// workspace layout (bytes)
#define OFF_BF    0                         // 128 floats
#define OFF_STATE 512                       // 32 * 32B
#define OFF_CNT   1536                      // 32 * 4B
#define OFF_HIST1 2048                      // 32*4096*4 = 512KB
#define OFF_HIST2 (OFF_HIST1 + 4*NBIN*NROW)
#define OFF_EQ    (OFF_HIST2 + 4*NBIN*NROW) // 32*8192*8 = 2MB

__device__ __forceinline__ unsigned sortkey(float f) {
    unsigned u = __float_as_uint(f);
    return (u & 0x80000000u) ? ~u : (u | 0x80000000u);
}

__global__ void k_zero(unsigned* p, int nwords) {
    int i = blockIdx.x * blockDim.x + threadIdx.x;
    if (i < nwords) p[i] = 0;
}

__global__ void k_boost(const float* duty, const float* bsp, const int* kp, float* bf) {
    int c = threadIdx.x;
    if (c < NCH) {
        float bs = fmaxf(bsp[0], 0.0f);
        float td = (float)kp[0] / (float)NPR;     // jnp.float32(k)/jnp.float32(n)
        float arg = (td - duty[c]) * bs;          // f32 ops match reference
        bf[c] = (float)exp((double)arg);          // correctly-rounded f32 exp
    }
}

template <int LEVEL>
__global__ __launch_bounds__(256) void k_hist(const float* __restrict__ x,
                                              const float* __restrict__ bf,
                                              unsigned* __restrict__ ghist,
                                              const RowState* __restrict__ st) {
    __shared__ unsigned h[NBIN];
    __shared__ float bfs[NCH];
    int tid = threadIdx.x;
    for (int i = tid; i < NBIN; i += 256) h[i] = 0;
    if (tid < NCH) bfs[tid] = bf[tid];
    __syncthreads();

    int row = blockIdx.y;
    unsigned p1 = 0;
    if (LEVEL == 2) p1 = st[row].p1;
    const int chunk = N4 / gridDim.x;   // exact division by construction
    const float4* xr = (const float4*)(x + (size_t)row * NPR) + (size_t)blockIdx.x * chunk;
    int base_j = blockIdx.x * chunk * 4;

    for (int i = tid; i < chunk; i += 256) {
        float4 v = xr[i];
        int j = base_j + i * 4;
        int c = j & (NCH - 1);
        unsigned k0 = sortkey(v.x * bfs[c]);
        unsigned k1 = sortkey(v.y * bfs[c + 1]);
        unsigned k2 = sortkey(v.z * bfs[c + 2]);
        unsigned k3 = sortkey(v.w * bfs[c + 3]);
        if (LEVEL == 1) {
            atomicAdd(&h[k0 >> 20], 1u);
            atomicAdd(&h[k1 >> 20], 1u);
            atomicAdd(&h[k2 >> 20], 1u);
            atomicAdd(&h[k3 >> 20], 1u);
        } else {
            if ((k0 >> 20) == p1) atomicAdd(&h[(k0 >> 8) & 0xFFFu], 1u);
            if ((k1 >> 20) == p1) atomicAdd(&h[(k1 >> 8) & 0xFFFu], 1u);
            if ((k2 >> 20) == p1) atomicAdd(&h[(k2 >> 8) & 0xFFFu], 1u);
            if ((k3 >> 20) == p1) atomicAdd(&h[(k3 >> 8) & 0xFFFu], 1u);
        }
    }
    __syncthreads();
    unsigned* gh = ghist + (size_t)row * NBIN;
    for (int i = tid; i < NBIN; i += 256)
        if (h[i]) atomicAdd(&gh[i], h[i]);
}

template <int LEVEL>
__global__ __launch_bounds__(256) void k_scan(const unsigned* __restrict__ ghist,
                                              RowState* st, const int* kp) {
    __shared__ unsigned hh[NBIN];
    __shared__ unsigned psum[256];
    int row = blockIdx.x;
    int tid = threadIdx.x;
    const unsigned* gh = ghist + (size_t)row * NBIN;
    for (int i = tid; i < NBIN; i += 256) hh[i] = gh[i];
    __syncthreads();
    unsigned target = (LEVEL == 1) ? (unsigned)kp[0] : st[row].krem1;

    // thread t owns reverse-order positions [t*16, t*16+16): bin = 4095 - pos
    unsigned s = 0;
    for (int q = 0; q < 16; ++q) s += hh[4095 - (tid * 16 + q)];
    psum[tid] = s;
    __syncthreads();
    if (tid == 0) {
        unsigned acc = 0;
        for (int t = 0; t < 256; ++t) { unsigned v = psum[t]; psum[t] = acc; acc += v; }
    }
    __syncthreads();
    unsigned cum = psum[tid];
    for (int q = 0; q < 16; ++q) {
        int bin = 4095 - (tid * 16 + q);
        unsigned cnt = hh[bin];
        if (cum < target && cum + cnt >= target) {
            if (LEVEL == 1) {
                st[row].p1 = (unsigned)bin;
                st[row].krem1 = target - cum;
            } else {
                st[row].p2 = (st[row].p1 << 12) | (unsigned)bin;
                st[row].krem2 = target - cum;
            }
        }
        cum += cnt;
    }
}

__global__ __launch_bounds__(256) void k_collect(const float* __restrict__ x,
                                                 const float* __restrict__ bf,
                                                 const RowState* __restrict__ st,
                                                 unsigned* cnt, uint2* eq) {
    __shared__ float bfs[NCH];
    int tid = threadIdx.x;
    if (tid < NCH) bfs[tid] = bf[tid];
    __syncthreads();
    int row = blockIdx.y;
    unsigned p2 = st[row].p2;
    const int chunk = N4 / gridDim.x;
    const float4* xr = (const float4*)(x + (size_t)row * NPR) + (size_t)blockIdx.x * chunk;
    int base_j = blockIdx.x * chunk * 4;
    uint2* eqr = eq + (size_t)row * EQCAP;
    for (int i = tid; i < chunk; i += 256) {
        float4 v = xr[i];
        int j = base_j + i * 4;
        int c = j & (NCH - 1);
        float b[4] = { v.x * bfs[c], v.y * bfs[c + 1], v.z * bfs[c + 2], v.w * bfs[c + 3] };
#pragma unroll
        for (int t = 0; t < 4; ++t) {
            unsigned key = sortkey(b[t]);
            if ((key >> 8) == p2) {
                unsigned pos = atomicAdd(&cnt[row], 1u);
                if (pos < EQCAP) eqr[pos] = make_uint2((unsigned)(j + t), key);
            }
        }
    }
}

__global__ __launch_bounds__(256) void k_select(const unsigned* __restrict__ cnt,
                                                const uint2* __restrict__ eq,
                                                RowState* st) {
    __shared__ uint2 se[EQCAP];
    int row = blockIdx.x;
    int tid = threadIdx.x;
    unsigned m = min(cnt[row], (unsigned)EQCAP);
    unsigned quota = st[row].krem2;   // >= 1 by construction
    const uint2* eqr = eq + (size_t)row * EQCAP;
    for (unsigned i = tid; i < m; i += 256) se[i] = eqr[i];
    __syncthreads();
    // rank by (key desc, idx asc) == jax.lax.top_k tie-break (lower index first)
    for (unsigned i = tid; i < m; i += 256) {
        unsigned long long s = ((unsigned long long)se[i].y << 32) | (unsigned)(~se[i].x);
        unsigned rank = 0;
        for (unsigned j = 0; j < m; ++j) {
            unsigned long long s2 = ((unsigned long long)se[j].y << 32) | (unsigned)(~se[j].x);
            rank += (s2 > s) ? 1u : 0u;
        }
        if (rank == quota - 1) {
            st[row].tkey = se[i].y;
            st[row].cutoff = se[i].x;
        }
    }
}

__global__ __launch_bounds__(256) void k_mask(const float* __restrict__ x,
                                              const float* __restrict__ bf,
                                              const RowState* __restrict__ st,
                                              float* __restrict__ out) {
    __shared__ float bfs[NCH];
    int tid = threadIdx.x;
    if (tid < NCH) bfs[tid] = bf[tid];
    __syncthreads();
    int row = blockIdx.y;
    unsigned tkey = st[row].tkey;
    unsigned cutoff = st[row].cutoff;
    const int chunk = N4 / gridDim.x;
    const float4* xr = (const float4*)(x + (size_t)row * NPR) + (size_t)blockIdx.x * chunk;
    float4* outr = (float4*)(out + (size_t)row * NPR) + (size_t)blockIdx.x * chunk;
    int base_j = blockIdx.x * chunk * 4;
    for (int i = tid; i < chunk; i += 256) {
        float4 v = xr[i];
        int j = base_j + i * 4;
        int c = j & (NCH - 1);
        unsigned k0 = sortkey(v.x * bfs[c]);
        unsigned k1 = sortkey(v.y * bfs[c + 1]);
        unsigned k2 = sortkey(v.z * bfs[c + 2]);
        unsigned k3 = sortkey(v.w * bfs[c + 3]);
        float4 o;
        o.x = (k0 > tkey || (k0 == tkey && (unsigned)(j + 0) <= cutoff)) ? v.x : 0.0f;
        o.y = (k1 > tkey || (k1 == tkey && (unsigned)(j + 1) <= cutoff)) ? v.y : 0.0f;
        o.z = (k2 > tkey || (k2 == tkey && (unsigned)(j + 2) <= cutoff)) ? v.z : 0.0f;
        o.w = (k3 > tkey || (k3 == tkey && (unsigned)(j + 3) <= cutoff)) ? v.w : 0.0f;
        outr[i] = o;
    }
}

extern "C" void kernel_launch(void* const* d_in, const int* in_sizes, int n_in,
                              void* d_out, int out_size, void* d_ws, size_t ws_size,
                              hipStream_t stream) {
    const float* x    = (const float*)d_in[0];
    const float* duty = (const float*)d_in[1];
    const float* bsp  = (const float*)d_in[2];
    const int*   kp   = (const int*)d_in[3];
    float* out = (float*)d_out;

    char* ws = (char*)d_ws;
    float*    bf  = (float*)(ws + OFF_BF);
    RowState* st  = (RowState*)(ws + OFF_STATE);
    unsigned* cnt = (unsigned*)(ws + OFF_CNT);
    unsigned* h1  = (unsigned*)(ws + OFF_HIST1);
    unsigned* h2  = (unsigned*)(ws + OFF_HIST2);
    uint2*    eq  = (uint2*)(ws + OFF_EQ);

    // zero cnt + both histograms (ws is poisoned 0xAA before every launch)
    {
        int nwords = (OFF_EQ - OFF_CNT) / 4;
        int nb = (nwords + 255) / 256;
        k_zero<<<nb, 256, 0, stream>>>((unsigned*)(ws + OFF_CNT), nwords);
    }
    k_boost<<<1, 128, 0, stream>>>(duty, bsp, kp, bf);

    dim3 g16(16, NROW);
    dim3 g32(32, NROW);
    k_hist<1><<<g16, 256, 0, stream>>>(x, bf, h1, st);
    k_scan<1><<<NROW, 256, 0, stream>>>(h1, st, kp);
    k_hist<2><<<g16, 256, 0, stream>>>(x, bf, h2, st);
    k_scan<2><<<NROW, 256, 0, stream>>>(h2, st, kp);
    k_collect<<<g16, 256, 0, stream>>>(x, bf, st, cnt, eq);
    k_select<<<NROW, 256, 0, stream>>>(cnt, eq, st);
    k_mask<<<g32, 256, 0, stream>>>(x, bf, st, out);
}